// Round 9
// baseline (162.196 us; speedup 1.0000x reference)
//
#include <hip/hip_runtime.h>
#include <hip/hip_bf16.h>

// Node_GAT N=16, M=1024, D=64, H=4.
// R13 = R12 (LDS-free attn j-loop, frag-major Q/V^T, reg double-buffer) + DEC FUSION:
// dec kernel and DX buffer deleted. out = sum_h dx_h @ Wdec_h^T + bdec is a head-sum,
// so attn blocks now own ALL 4 heads of 64 output rows: grid (16 iblk, 16 n), 512 thr
// = 8 waves, wave = (istrip = w>>2, head = w&3). j-loop per wave identical to R12.
// Epilogue: dx -> wave-local LDS transpose -> 8 dec-MFMA vs Wdec head-slice ->
// LDS atomicAdd (ds_add_f32) head-sum -> barrier -> +bdec, coalesced fp32 out store.
// No global atomics (out fully written; poison-safe). Bias added once in store phase.

#define NB 16
#define MM 1024
#define DD 64
#define HH 4
#define NEG 0.2f
#define AST 72   // LDS row stride (shorts): 16B-aligned rows
#define OST 65   // out-accum LDS stride (floats)
#define LOG2E 1.44269504088896f

typedef __attribute__((ext_vector_type(8))) short bf16x8;
typedef __attribute__((ext_vector_type(8))) _Float16 f16x8;
typedef __attribute__((ext_vector_type(16))) float f32x16;
typedef __attribute__((ext_vector_type(4))) unsigned int uint4v;
typedef __attribute__((ext_vector_type(2))) unsigned int uint2v;

__device__ inline unsigned short f2bf(float f) {
  unsigned int u = __builtin_bit_cast(unsigned int, f);
  unsigned int r = (u + 0x7FFFu + ((u >> 16) & 1u)) >> 16;
  return (unsigned short)r;
}
__device__ inline unsigned short f2h(float f) {
  _Float16 h = (_Float16)f;
  return __builtin_bit_cast(unsigned short, h);
}
__device__ inline unsigned int pk_bf16(float lo, float hi) {
  unsigned int r;
  asm("v_cvt_pk_bf16_f32 %0, %1, %2" : "=v"(r) : "v"(lo), "v"(hi));
  return r;
}
// swap32(a,b): a' = {hf0: own.a, hf1: partner.b}; b' = {hf0: partner.a, hf1: own.b}
__device__ inline void swap32(unsigned int& a, unsigned int& b) {
  uint2v r = __builtin_amdgcn_permlane32_swap(a, b, false, false);
  a = r.x;
  b = r.y;
}

// ---------------- Kernel 0: weight prep -> f16 ----------------
__global__ __launch_bounds__(256) void prep_kernel(
    const float* __restrict__ Wk, const float* __restrict__ Wq,
    const float* __restrict__ Wv, const float* __restrict__ Wdec,
    unsigned short* __restrict__ Wf) {
  const int idx = (blockIdx.x * 256 + threadIdx.x) * 4;
  const int seg = idx >> 14, local = idx & 16383;
  const float* src = seg == 0 ? Wk : seg == 1 ? Wq : seg == 2 ? Wv : Wdec;
  float4 v = *(const float4*)&src[local];
  unsigned short p[4] = {f2h(v.x), f2h(v.y), f2h(v.z), f2h(v.w)};
  *(uint2*)&Wf[idx] = *(uint2*)p;
}

// ---------------- Kernel 1: projections, f16 32x32x16 MFMA ----------------
// grid (256, 12): 64 m-rows x combo(mat*4+h). K (scaled by log2e) -> linear f16;
// Q -> FRAG-MAJOR f16; V -> FRAG-MAJOR V^T bf16.
__global__ __launch_bounds__(256) void proj_kernel(
    const float* __restrict__ x, const unsigned short* __restrict__ Wf,
    const float* __restrict__ bk, const float* __restrict__ bq, const float* __restrict__ bv,
    unsigned short* __restrict__ Kf, unsigned short* __restrict__ Qf,
    unsigned short* __restrict__ Vtg) {
  __shared__ unsigned short xs[64 * AST];
  __shared__ unsigned short ob[64 * AST];
  const int t = threadIdx.x;
  const int r0 = blockIdx.x * 64;
  const int combo = blockIdx.y, mat = combo >> 2, h = combo & 3;
  const int n = r0 >> 10, ml = r0 & 1023;
  const float* bias = mat == 0 ? bk : (mat == 1 ? bq : bv);

#pragma unroll
  for (int rep = 0; rep < 2; ++rep) {
    int idx = rep * 256 + t, row = idx >> 3, c8 = (idx & 7) * 8;
    float4 a = *(const float4*)&x[(size_t)(r0 + row) * DD + c8];
    float4 b = *(const float4*)&x[(size_t)(r0 + row) * DD + c8 + 4];
    unsigned short p[8] = {f2h(a.x), f2h(a.y), f2h(a.z), f2h(a.w),
                           f2h(b.x), f2h(b.y), f2h(b.z), f2h(b.w)};
    *(uint4*)&xs[row * AST + c8] = *(uint4*)p;
  }
  __syncthreads();

  const int w = t >> 6, lane = t & 63, m31 = lane & 31, hf = lane >> 5;
  const int mi = w >> 1, ne = w & 1;
  const int ecol = h * 64 + ne * 32 + m31;
  const float bb = bias[ecol];

  f32x16 C;
#pragma unroll
  for (int r = 0; r < 16; ++r) C[r] = 0.f;
#pragma unroll
  for (int ks = 0; ks < 4; ++ks) {
    f16x8 xa = *(f16x8*)&xs[(mi * 32 + m31) * AST + ks * 16 + hf * 8];
    f16x8 wb = *(const f16x8*)&Wf[(size_t)mat * 16384 + (size_t)ecol * DD + ks * 16 + hf * 8];
    C = __builtin_amdgcn_mfma_f32_32x32x16_f16(xa, wb, C, 0, 0, 0);
  }

  if (mat < 2) {
    const float ksc = (mat == 0) ? LOG2E : 1.0f;  // fold exp's log2e into K
#pragma unroll
    for (int r = 0; r < 16; ++r) {
      int rr = (r & 3) + 8 * (r >> 2) + 4 * hf;
      ob[(mi * 32 + rr) * AST + ne * 32 + m31] = f2h((C[r] + bb) * ksc);
    }
  } else {
    // V transposed staging: ob[e][m_local], bf16
#pragma unroll
    for (int r = 0; r < 16; ++r) {
      int rr = (r & 3) + 8 * (r >> 2) + 4 * hf;
      ob[(ne * 32 + m31) * AST + mi * 32 + rr] = f2bf(C[r] + bb);
    }
  }
  __syncthreads();

  if (mat == 0) {
    // K: linear (n,h,m,e) — attn reads kfrag once per block
    const size_t obase = (((size_t)n * HH + h) * MM + ml) * DD;
#pragma unroll
    for (int rep = 0; rep < 2; ++rep) {
      int idx = rep * 256 + t, row = idx >> 3, c8 = (idx & 7) * 8;
      *(uint4*)&Kf[obase + (size_t)row * DD + c8] = *(uint4*)&ob[row * AST + c8];
    }
  } else if (mat == 1) {
    // Q frag-major: dst short-offset = base + ml*64 + idx*8, where
    // idx = jb32l*256 + ks*64 + hf2*32 + mr  <->  frag (jb32=ml/32+jb32l, ks, hf2, mr)
    const size_t obase = (((size_t)n * HH + h) * MM + ml) * DD;
#pragma unroll
    for (int rep = 0; rep < 2; ++rep) {
      int idx = rep * 256 + t;
      int jb32l = idx >> 8, ks = (idx >> 6) & 3, hf2 = (idx >> 5) & 1, mr = idx & 31;
      *(uint4*)&Qf[obase + (size_t)idx * 8] =
          *(uint4*)&ob[(jb32l * 32 + mr) * AST + ks * 16 + hf2 * 8];
    }
  } else {
    // V^T frag-major: dst short-offset = baseT + (ml/64)*4096 + idx*8, where
    // idx = ks*128 + eh*64 + hf2*32 + mr  <->  frag (jt=ml/64, ks, eh, hf2, mr)
    const size_t obaseT = (((size_t)n * HH + h) * DD) * MM + (size_t)(ml >> 6) * 4096;
#pragma unroll
    for (int rep = 0; rep < 2; ++rep) {
      int idx = rep * 256 + t;
      int ks = idx >> 7, eh = (idx >> 6) & 1, hf2 = (idx >> 5) & 1, mr = idx & 31;
      *(uint4*)&Vtg[obaseT + (size_t)idx * 8] =
          *(uint4*)&ob[(eh * 32 + mr) * AST + ks * 16 + hf2 * 8];
    }
  }
}

// ---------------- Kernel 2: fused attention + decoder ----------------
// grid (16 iblk, 16 n), 512 thr = 8 waves; wave = (istrip = w>>2, head = w&3).
// j-loop per wave: 16 coalesced frag loads (reg double-buffer, one tile ahead) +
// S^T mfma(Q,K) + in-reg softmax + PV. Zero LDS / zero barriers in loop.
// Epilogue: dx -> wave-local LDS transpose -> dec MFMA (head slice of Wdec) ->
// ds_add_f32 head-sum in LDS -> barrier -> +bdec, coalesced out store.

#define LOADF(qa0_, qa1_, bv0_, bv1_, jtn)                         \
  do {                                                             \
    const unsigned short* Qj_ = Qp + (size_t)(jtn) * 4096;         \
    const unsigned short* Vj_ = Vp + (size_t)(jtn) * 4096;         \
    _Pragma("unroll") for (int ks = 0; ks < 4; ++ks) {             \
      qa0_[ks] = *(const f16x8*)&Qj_[ks * 512 + loff];             \
      qa1_[ks] = *(const f16x8*)&Qj_[2048 + ks * 512 + loff];      \
      bv0_[ks] = *(const bf16x8*)&Vj_[ks * 1024 + loff];           \
      bv1_[ks] = *(const bf16x8*)&Vj_[ks * 1024 + 512 + loff];     \
    }                                                              \
  } while (0)

#define SOFTPACK(C_, dst0_, dst1_)                                             \
  do {                                                                         \
    _Pragma("unroll") for (int r = 0; r < 16; ++r) {                           \
      float s = C_[r];                                                         \
      s = fmaxf(s, NEG * s);                                                   \
      s = __builtin_amdgcn_exp2f(s);                                           \
      lac += s;                                                                \
      C_[r] = s;                                                               \
    }                                                                          \
    {                                                                          \
      unsigned int p01 = pk_bf16(C_[0], C_[1]), p23 = pk_bf16(C_[2], C_[3]);   \
      unsigned int p45 = pk_bf16(C_[4], C_[5]), p67 = pk_bf16(C_[6], C_[7]);   \
      swap32(p01, p45);                                                        \
      swap32(p23, p67);                                                        \
      uint4v wlo = {p01, p23, p45, p67};                                       \
      dst0_ = __builtin_bit_cast(bf16x8, wlo);                                 \
      unsigned int p89 = pk_bf16(C_[8], C_[9]), pAB = pk_bf16(C_[10], C_[11]); \
      unsigned int pCD = pk_bf16(C_[12], C_[13]), pEF = pk_bf16(C_[14], C_[15]); \
      swap32(p89, pCD);                                                        \
      swap32(pAB, pEF);                                                        \
      uint4v whi = {p89, pAB, pCD, pEF};                                       \
      dst1_ = __builtin_bit_cast(bf16x8, whi);                                 \
    }                                                                          \
  } while (0)

#define COMPUTE(qa0_, qa1_, bv0_, bv1_)                                         \
  do {                                                                          \
    bf16x8 pa[4];                                                               \
    f32x16 C;                                                                   \
    _Pragma("unroll") for (int r = 0; r < 16; ++r) C[r] = 0.f;                  \
    _Pragma("unroll") for (int ks = 0; ks < 4; ++ks)                            \
        C = __builtin_amdgcn_mfma_f32_32x32x16_f16(qa0_[ks], kfrag[ks], C, 0, 0, 0); \
    SOFTPACK(C, pa[0], pa[1]);                                                  \
    _Pragma("unroll") for (int r = 0; r < 16; ++r) C[r] = 0.f;                  \
    _Pragma("unroll") for (int ks = 0; ks < 4; ++ks)                            \
        C = __builtin_amdgcn_mfma_f32_32x32x16_f16(qa1_[ks], kfrag[ks], C, 0, 0, 0); \
    SOFTPACK(C, pa[2], pa[3]);                                                  \
    _Pragma("unroll") for (int ks = 0; ks < 4; ++ks) {                          \
      agg0 = __builtin_amdgcn_mfma_f32_32x32x16_bf16(pa[ks], bv0_[ks], agg0, 0, 0, 0); \
      agg1 = __builtin_amdgcn_mfma_f32_32x32x16_bf16(pa[ks], bv1_[ks], agg1, 0, 0, 0); \
    }                                                                           \
  } while (0)

__global__ __launch_bounds__(512, 2) void attn_kernel(
    const unsigned short* __restrict__ Kf, const unsigned short* __restrict__ Qf,
    const unsigned short* __restrict__ Vtg, const float* __restrict__ x,
    const unsigned short* __restrict__ Wdf, const float* __restrict__ bdec,
    float* __restrict__ out) {
  __shared__ __align__(16) unsigned short dxs[8 * 32 * AST];  // per-wave dx transpose
  __shared__ float outacc[64 * OST];                          // head-sum accumulator

  const int t = threadIdx.x;
  const int w = t >> 6, lane = t & 63;
  const int m31 = lane & 31, hf = lane >> 5;
  const int istrip = w >> 2, h = w & 3;

  // XCD-bijective swizzle: each XCD gets 32 consecutive slots (2 whole n's).
  const int slot = blockIdx.x + 16 * (int)blockIdx.y;  // 0..255
  const int val = (slot & 7) * 32 + (slot >> 3);
  const int n = val >> 4, ib = val & 15;
  const int i0 = ib * 64;

  // zero the out accumulator before any wave can reach the epilogue
  for (int idx = t; idx < 64 * OST; idx += 512) outacc[idx] = 0.f;
  __syncthreads();

  const size_t base = (((size_t)n * HH + h) * MM) * DD;
  const size_t baseT = (((size_t)n * HH + h) * DD) * MM;
  const unsigned short* Qp = Qf + base;
  const unsigned short* Vp = Vtg + baseT;

  // K fragments: B-operand cols i = i0 + istrip*32 + m31 (log2e pre-folded in proj)
  f16x8 kfrag[4];
#pragma unroll
  for (int ks = 0; ks < 4; ++ks)
    kfrag[ks] =
        *(const f16x8*)&Kf[base + (size_t)(i0 + istrip * 32 + m31) * DD + ks * 16 + hf * 8];

  f32x16 agg0, agg1;
#pragma unroll
  for (int r = 0; r < 16; ++r) { agg0[r] = 0.f; agg1[r] = 0.f; }
  float lac = 0.f;

  const int loff = hf * 256 + m31 * 8;  // lane term, shared by all frag loads

  // named double-buffer sets (all indices literal — rule #20)
  f16x8 Aq0[4], Aq1[4], Bq0[4], Bq1[4];
  bf16x8 Av0[4], Av1[4], Bv0[4], Bv1[4];

  LOADF(Aq0, Aq1, Av0, Av1, 0);
  for (int g = 0; g < 8; ++g) {
    LOADF(Bq0, Bq1, Bv0, Bv1, 2 * g + 1);             // prefetch odd tile
    COMPUTE(Aq0, Aq1, Av0, Av1);                      // compute even tile
    if (g < 7) LOADF(Aq0, Aq1, Av0, Av1, 2 * g + 2);  // prefetch next even tile
    COMPUTE(Bq0, Bq1, Bv0, Bv1);                      // compute odd tile
  }

  // denom: lsum(lane) = l[row m31] (both halves); broadcast to row rr via shfl.
  const float lsum = lac + __shfl_xor(lac, 32);

  // dx = leaky(agg/l) - x -> f16 into this wave's transpose region (lane=e -> lane=i)
  unsigned short* dxw = dxs + w * (32 * AST);
#pragma unroll
  for (int r = 0; r < 16; ++r) {
    const int rr = (r & 3) + 8 * (r >> 2) + 4 * hf;
    const float rl = 1.0f / __shfl(lsum, rr);
    const size_t xrow = ((size_t)n * MM + i0 + istrip * 32 + rr) * DD;
    float v0 = agg0[r] * rl;
    v0 = fmaxf(v0, NEG * v0);
    v0 -= x[xrow + m31];
    dxw[rr * AST + m31] = f2h(v0);
    float v1 = agg1[r] * rl;
    v1 = fmaxf(v1, NEG * v1);
    v1 -= x[xrow + 32 + m31];
    dxw[rr * AST + 32 + m31] = f2h(v1);
  }

  // dec partial: out_part[32 i][64 o] = dx[32 i][64 e] @ Wdec[o][h*64+e]^T
  f32x16 Co0, Co1;
#pragma unroll
  for (int r = 0; r < 16; ++r) { Co0[r] = 0.f; Co1[r] = 0.f; }
#pragma unroll
  for (int ks = 0; ks < 4; ++ks) {
    f16x8 aD = *(f16x8*)&dxw[m31 * AST + ks * 16 + hf * 8];  // wave-local read-after-write
    f16x8 w0 = *(const f16x8*)&Wdf[(size_t)m31 * 256 + h * 64 + ks * 16 + hf * 8];
    f16x8 w1 = *(const f16x8*)&Wdf[(size_t)(32 + m31) * 256 + h * 64 + ks * 16 + hf * 8];
    Co0 = __builtin_amdgcn_mfma_f32_32x32x16_f16(aD, w0, Co0, 0, 0, 0);
    Co1 = __builtin_amdgcn_mfma_f32_32x32x16_f16(aD, w1, Co1, 0, 0, 0);
  }

  // head-sum into LDS accumulator (4 head-waves per i-strip)
#pragma unroll
  for (int r = 0; r < 16; ++r) {
    const int rr = (r & 3) + 8 * (r >> 2) + 4 * hf;
    atomicAdd(&outacc[(istrip * 32 + rr) * OST + m31], Co0[r]);
    atomicAdd(&outacc[(istrip * 32 + rr) * OST + 32 + m31], Co1[r]);
  }
  __syncthreads();

  // store: out[n, i0+row, :] = outacc[row] + bdec (block fully owns these 64 rows)
#pragma unroll
  for (int rep = 0; rep < 2; ++rep) {
    const int idx = rep * 512 + t;
    const int row = idx >> 4, c4 = (idx & 15) * 4;
    float4 v;
    v.x = outacc[row * OST + c4 + 0] + bdec[c4 + 0];
    v.y = outacc[row * OST + c4 + 1] + bdec[c4 + 1];
    v.z = outacc[row * OST + c4 + 2] + bdec[c4 + 2];
    v.w = outacc[row * OST + c4 + 3] + bdec[c4 + 3];
    *(float4*)&out[((size_t)n * MM + i0 + row) * DD + c4] = v;
  }
}

extern "C" void kernel_launch(void* const* d_in, const int* in_sizes, int n_in,
                              void* d_out, int out_size, void* d_ws, size_t ws_size,
                              hipStream_t stream) {
  const float* x    = (const float*)d_in[0];
  const float* Wk   = (const float*)d_in[2];
  const float* bk   = (const float*)d_in[3];
  const float* Wq   = (const float*)d_in[4];
  const float* bq   = (const float*)d_in[5];
  const float* Wv   = (const float*)d_in[6];
  const float* bv   = (const float*)d_in[7];
  const float* Wdec = (const float*)d_in[8];
  const float* bdec = (const float*)d_in[9];
  float* out = (float*)d_out;

  const size_t seg = (size_t)NB * HH * MM * DD;
  unsigned short* Kf  = (unsigned short*)d_ws;
  unsigned short* Qf  = Kf + seg;
  unsigned short* Vt  = Qf + seg;
  unsigned short* DXp = Vt + seg;  // unused (dec fused); kept for ws layout stability
  unsigned short* Wf  = DXp + seg;
  unsigned short* Wdf = Wf + 3 * 16384;

  prep_kernel<<<64, 256, 0, stream>>>(Wk, Wq, Wv, Wdec, Wf);
  proj_kernel<<<dim3(256, 12), 256, 0, stream>>>(x, Wf, bk, bq, bv, Kf, Qf, Vt);
  attn_kernel<<<dim3(16, 16), 512, 0, stream>>>(Kf, Qf, Vt, x, Wdf, bdec, out);
}

// Round 10
// 162.026 us; speedup vs baseline: 1.0010x; 1.0010x over previous
//
#include <hip/hip_runtime.h>
#include <hip/hip_bf16.h>

// Node_GAT N=16, M=1024, D=64, H=4.
// R14 = R13's dec-fusion RESTRUCTURED to R12's proven compilation shape:
// R13 (512-thr blocks) compiled to VGPR=120 — too few for the 4 reg-dbuf sets
// (~128 VGPR) -> compiler sank loads, pipeline silently deleted, attn 57.9us with
// R11's exposed-latency signature. R14: 256-thr blocks / 4 waves, launch_bounds(256,2)
// (identical to R12's attn which achieved the pipeline at ~33us). Wave = head;
// block owns 32 i-rows x all 4 heads; grid (32 iblk, 16 n) = 512 blocks.
// j-loop macros byte-identical to R12. Epilogue: dx -> wave-local LDS transpose ->
// dec MFMA (head slice of Wdec) -> LDS atomicAdd head-sum -> barrier -> +bdec store.
// dec kernel + DX buffer stay deleted.

#define NB 16
#define MM 1024
#define DD 64
#define HH 4
#define NEG 0.2f
#define AST 72   // LDS row stride (shorts): 16B-aligned rows
#define OST 65   // out-accum LDS stride (floats)
#define LOG2E 1.44269504088896f

typedef __attribute__((ext_vector_type(8))) short bf16x8;
typedef __attribute__((ext_vector_type(8))) _Float16 f16x8;
typedef __attribute__((ext_vector_type(16))) float f32x16;
typedef __attribute__((ext_vector_type(4))) unsigned int uint4v;
typedef __attribute__((ext_vector_type(2))) unsigned int uint2v;

__device__ inline unsigned short f2bf(float f) {
  unsigned int u = __builtin_bit_cast(unsigned int, f);
  unsigned int r = (u + 0x7FFFu + ((u >> 16) & 1u)) >> 16;
  return (unsigned short)r;
}
__device__ inline unsigned short f2h(float f) {
  _Float16 h = (_Float16)f;
  return __builtin_bit_cast(unsigned short, h);
}
__device__ inline unsigned int pk_bf16(float lo, float hi) {
  unsigned int r;
  asm("v_cvt_pk_bf16_f32 %0, %1, %2" : "=v"(r) : "v"(lo), "v"(hi));
  return r;
}
// swap32(a,b): a' = {hf0: own.a, hf1: partner.b}; b' = {hf0: partner.a, hf1: own.b}
__device__ inline void swap32(unsigned int& a, unsigned int& b) {
  uint2v r = __builtin_amdgcn_permlane32_swap(a, b, false, false);
  a = r.x;
  b = r.y;
}

// ---------------- Kernel 0: weight prep -> f16 ----------------
__global__ __launch_bounds__(256) void prep_kernel(
    const float* __restrict__ Wk, const float* __restrict__ Wq,
    const float* __restrict__ Wv, const float* __restrict__ Wdec,
    unsigned short* __restrict__ Wf) {
  const int idx = (blockIdx.x * 256 + threadIdx.x) * 4;
  const int seg = idx >> 14, local = idx & 16383;
  const float* src = seg == 0 ? Wk : seg == 1 ? Wq : seg == 2 ? Wv : Wdec;
  float4 v = *(const float4*)&src[local];
  unsigned short p[4] = {f2h(v.x), f2h(v.y), f2h(v.z), f2h(v.w)};
  *(uint2*)&Wf[idx] = *(uint2*)p;
}

// ---------------- Kernel 1: projections, f16 32x32x16 MFMA ----------------
// grid (256, 12): 64 m-rows x combo(mat*4+h). K (scaled by log2e) -> linear f16;
// Q -> FRAG-MAJOR f16; V -> FRAG-MAJOR V^T bf16.
__global__ __launch_bounds__(256) void proj_kernel(
    const float* __restrict__ x, const unsigned short* __restrict__ Wf,
    const float* __restrict__ bk, const float* __restrict__ bq, const float* __restrict__ bv,
    unsigned short* __restrict__ Kf, unsigned short* __restrict__ Qf,
    unsigned short* __restrict__ Vtg) {
  __shared__ unsigned short xs[64 * AST];
  __shared__ unsigned short ob[64 * AST];
  const int t = threadIdx.x;
  const int r0 = blockIdx.x * 64;
  const int combo = blockIdx.y, mat = combo >> 2, h = combo & 3;
  const int n = r0 >> 10, ml = r0 & 1023;
  const float* bias = mat == 0 ? bk : (mat == 1 ? bq : bv);

#pragma unroll
  for (int rep = 0; rep < 2; ++rep) {
    int idx = rep * 256 + t, row = idx >> 3, c8 = (idx & 7) * 8;
    float4 a = *(const float4*)&x[(size_t)(r0 + row) * DD + c8];
    float4 b = *(const float4*)&x[(size_t)(r0 + row) * DD + c8 + 4];
    unsigned short p[8] = {f2h(a.x), f2h(a.y), f2h(a.z), f2h(a.w),
                           f2h(b.x), f2h(b.y), f2h(b.z), f2h(b.w)};
    *(uint4*)&xs[row * AST + c8] = *(uint4*)p;
  }
  __syncthreads();

  const int w = t >> 6, lane = t & 63, m31 = lane & 31, hf = lane >> 5;
  const int mi = w >> 1, ne = w & 1;
  const int ecol = h * 64 + ne * 32 + m31;
  const float bb = bias[ecol];

  f32x16 C;
#pragma unroll
  for (int r = 0; r < 16; ++r) C[r] = 0.f;
#pragma unroll
  for (int ks = 0; ks < 4; ++ks) {
    f16x8 xa = *(f16x8*)&xs[(mi * 32 + m31) * AST + ks * 16 + hf * 8];
    f16x8 wb = *(const f16x8*)&Wf[(size_t)mat * 16384 + (size_t)ecol * DD + ks * 16 + hf * 8];
    C = __builtin_amdgcn_mfma_f32_32x32x16_f16(xa, wb, C, 0, 0, 0);
  }

  if (mat < 2) {
    const float ksc = (mat == 0) ? LOG2E : 1.0f;  // fold exp's log2e into K
#pragma unroll
    for (int r = 0; r < 16; ++r) {
      int rr = (r & 3) + 8 * (r >> 2) + 4 * hf;
      ob[(mi * 32 + rr) * AST + ne * 32 + m31] = f2h((C[r] + bb) * ksc);
    }
  } else {
    // V transposed staging: ob[e][m_local], bf16
#pragma unroll
    for (int r = 0; r < 16; ++r) {
      int rr = (r & 3) + 8 * (r >> 2) + 4 * hf;
      ob[(ne * 32 + m31) * AST + mi * 32 + rr] = f2bf(C[r] + bb);
    }
  }
  __syncthreads();

  if (mat == 0) {
    // K: linear (n,h,m,e) — attn reads kfrag once per block
    const size_t obase = (((size_t)n * HH + h) * MM + ml) * DD;
#pragma unroll
    for (int rep = 0; rep < 2; ++rep) {
      int idx = rep * 256 + t, row = idx >> 3, c8 = (idx & 7) * 8;
      *(uint4*)&Kf[obase + (size_t)row * DD + c8] = *(uint4*)&ob[row * AST + c8];
    }
  } else if (mat == 1) {
    // Q frag-major: dst short-offset = base + ml*64 + idx*8, where
    // idx = jb32l*256 + ks*64 + hf2*32 + mr  <->  frag (jb32=ml/32+jb32l, ks, hf2, mr)
    const size_t obase = (((size_t)n * HH + h) * MM + ml) * DD;
#pragma unroll
    for (int rep = 0; rep < 2; ++rep) {
      int idx = rep * 256 + t;
      int jb32l = idx >> 8, ks = (idx >> 6) & 3, hf2 = (idx >> 5) & 1, mr = idx & 31;
      *(uint4*)&Qf[obase + (size_t)idx * 8] =
          *(uint4*)&ob[(jb32l * 32 + mr) * AST + ks * 16 + hf2 * 8];
    }
  } else {
    // V^T frag-major: dst short-offset = baseT + (ml/64)*4096 + idx*8, where
    // idx = ks*128 + eh*64 + hf2*32 + mr  <->  frag (jt=ml/64, ks, eh, hf2, mr)
    const size_t obaseT = (((size_t)n * HH + h) * DD) * MM + (size_t)(ml >> 6) * 4096;
#pragma unroll
    for (int rep = 0; rep < 2; ++rep) {
      int idx = rep * 256 + t;
      int ks = idx >> 7, eh = (idx >> 6) & 1, hf2 = (idx >> 5) & 1, mr = idx & 31;
      *(uint4*)&Vtg[obaseT + (size_t)idx * 8] =
          *(uint4*)&ob[(eh * 32 + mr) * AST + ks * 16 + hf2 * 8];
    }
  }
}

// ---------------- Kernel 2: fused attention + decoder ----------------
// grid (32 iblk, 16 n), 256 thr = 4 waves; wave w = head h. Block owns 32 i-rows.
// j-loop per wave (identical to R12): 16 coalesced frag loads, reg double-buffer one
// tile ahead, S^T mfma(Q,K) + in-reg softmax + PV. Zero LDS / zero barriers in loop.
// Epilogue: dx -> wave-local LDS transpose -> dec MFMA (head slice of Wdec) ->
// ds_add_f32 head-sum -> barrier -> +bdec, coalesced fp32 out store.

#define LOADF(qa0_, qa1_, bv0_, bv1_, jtn)                         \
  do {                                                             \
    const unsigned short* Qj_ = Qp + (size_t)(jtn) * 4096;         \
    const unsigned short* Vj_ = Vp + (size_t)(jtn) * 4096;         \
    _Pragma("unroll") for (int ks = 0; ks < 4; ++ks) {             \
      qa0_[ks] = *(const f16x8*)&Qj_[ks * 512 + loff];             \
      qa1_[ks] = *(const f16x8*)&Qj_[2048 + ks * 512 + loff];      \
      bv0_[ks] = *(const bf16x8*)&Vj_[ks * 1024 + loff];           \
      bv1_[ks] = *(const bf16x8*)&Vj_[ks * 1024 + 512 + loff];     \
    }                                                              \
  } while (0)

#define SOFTPACK(C_, dst0_, dst1_)                                             \
  do {                                                                         \
    _Pragma("unroll") for (int r = 0; r < 16; ++r) {                           \
      float s = C_[r];                                                         \
      s = fmaxf(s, NEG * s);                                                   \
      s = __builtin_amdgcn_exp2f(s);                                           \
      lac += s;                                                                \
      C_[r] = s;                                                               \
    }                                                                          \
    {                                                                          \
      unsigned int p01 = pk_bf16(C_[0], C_[1]), p23 = pk_bf16(C_[2], C_[3]);   \
      unsigned int p45 = pk_bf16(C_[4], C_[5]), p67 = pk_bf16(C_[6], C_[7]);   \
      swap32(p01, p45);                                                        \
      swap32(p23, p67);                                                        \
      uint4v wlo = {p01, p23, p45, p67};                                       \
      dst0_ = __builtin_bit_cast(bf16x8, wlo);                                 \
      unsigned int p89 = pk_bf16(C_[8], C_[9]), pAB = pk_bf16(C_[10], C_[11]); \
      unsigned int pCD = pk_bf16(C_[12], C_[13]), pEF = pk_bf16(C_[14], C_[15]); \
      swap32(p89, pCD);                                                        \
      swap32(pAB, pEF);                                                        \
      uint4v whi = {p89, pAB, pCD, pEF};                                       \
      dst1_ = __builtin_bit_cast(bf16x8, whi);                                 \
    }                                                                          \
  } while (0)

#define COMPUTE(qa0_, qa1_, bv0_, bv1_)                                         \
  do {                                                                          \
    bf16x8 pa[4];                                                               \
    f32x16 C;                                                                   \
    _Pragma("unroll") for (int r = 0; r < 16; ++r) C[r] = 0.f;                  \
    _Pragma("unroll") for (int ks = 0; ks < 4; ++ks)                            \
        C = __builtin_amdgcn_mfma_f32_32x32x16_f16(qa0_[ks], kfrag[ks], C, 0, 0, 0); \
    SOFTPACK(C, pa[0], pa[1]);                                                  \
    _Pragma("unroll") for (int r = 0; r < 16; ++r) C[r] = 0.f;                  \
    _Pragma("unroll") for (int ks = 0; ks < 4; ++ks)                            \
        C = __builtin_amdgcn_mfma_f32_32x32x16_f16(qa1_[ks], kfrag[ks], C, 0, 0, 0); \
    SOFTPACK(C, pa[2], pa[3]);                                                  \
    _Pragma("unroll") for (int ks = 0; ks < 4; ++ks) {                          \
      agg0 = __builtin_amdgcn_mfma_f32_32x32x16_bf16(pa[ks], bv0_[ks], agg0, 0, 0, 0); \
      agg1 = __builtin_amdgcn_mfma_f32_32x32x16_bf16(pa[ks], bv1_[ks], agg1, 0, 0, 0); \
    }                                                                           \
  } while (0)

__global__ __launch_bounds__(256, 2) void attn_kernel(
    const unsigned short* __restrict__ Kf, const unsigned short* __restrict__ Qf,
    const unsigned short* __restrict__ Vtg, const float* __restrict__ x,
    const unsigned short* __restrict__ Wdf, const float* __restrict__ bdec,
    float* __restrict__ out) {
  __shared__ __align__(16) unsigned short dxs[4 * 32 * AST];  // per-wave dx transpose
  __shared__ float outacc[32 * OST];                          // head-sum accumulator

  const int t = threadIdx.x;
  const int w = t >> 6, lane = t & 63;   // w = head
  const int m31 = lane & 31, hf = lane >> 5;
  const int h = w;

  // XCD-bijective swizzle: each XCD owns 2 whole n's (all 32 iblocks each).
  const int slot = blockIdx.x + 32 * (int)blockIdx.y;  // 0..511
  const int val = (slot & 7) * 64 + (slot >> 3);
  const int n = val >> 5, ib = val & 31;
  const int i0 = ib * 32;

  // zero the out accumulator before epilogue use
  for (int idx = t; idx < 32 * OST; idx += 256) outacc[idx] = 0.f;

  const size_t base = (((size_t)n * HH + h) * MM) * DD;
  const size_t baseT = (((size_t)n * HH + h) * DD) * MM;
  const unsigned short* Qp = Qf + base;
  const unsigned short* Vp = Vtg + baseT;

  // K fragments: B-operand cols i = i0 + m31 (log2e pre-folded in proj)
  f16x8 kfrag[4];
#pragma unroll
  for (int ks = 0; ks < 4; ++ks)
    kfrag[ks] = *(const f16x8*)&Kf[base + (size_t)(i0 + m31) * DD + ks * 16 + hf * 8];

  f32x16 agg0, agg1;
#pragma unroll
  for (int r = 0; r < 16; ++r) { agg0[r] = 0.f; agg1[r] = 0.f; }
  float lac = 0.f;

  const int loff = hf * 256 + m31 * 8;  // lane term, shared by all frag loads

  // named double-buffer sets (all indices literal — rule #20)
  f16x8 Aq0[4], Aq1[4], Bq0[4], Bq1[4];
  bf16x8 Av0[4], Av1[4], Bv0[4], Bv1[4];

  LOADF(Aq0, Aq1, Av0, Av1, 0);
  for (int g = 0; g < 8; ++g) {
    LOADF(Bq0, Bq1, Bv0, Bv1, 2 * g + 1);             // prefetch odd tile
    COMPUTE(Aq0, Aq1, Av0, Av1);                      // compute even tile
    if (g < 7) LOADF(Aq0, Aq1, Av0, Av1, 2 * g + 2);  // prefetch next even tile
    COMPUTE(Bq0, Bq1, Bv0, Bv1);                      // compute odd tile
  }

  // denom: lsum(lane) = l[row m31] (both halves); broadcast to row rr via shfl.
  const float lsum = lac + __shfl_xor(lac, 32);

  // dx = leaky(agg/l) - x -> f16 into this wave's transpose region (lane=e -> lane=i)
  unsigned short* dxw = dxs + w * (32 * AST);
#pragma unroll
  for (int r = 0; r < 16; ++r) {
    const int rr = (r & 3) + 8 * (r >> 2) + 4 * hf;
    const float rl = 1.0f / __shfl(lsum, rr);
    const size_t xrow = ((size_t)n * MM + i0 + rr) * DD;
    float v0 = agg0[r] * rl;
    v0 = fmaxf(v0, NEG * v0);
    v0 -= x[xrow + m31];
    dxw[rr * AST + m31] = f2h(v0);
    float v1 = agg1[r] * rl;
    v1 = fmaxf(v1, NEG * v1);
    v1 -= x[xrow + 32 + m31];
    dxw[rr * AST + 32 + m31] = f2h(v1);
  }

  // dec partial: out_part[32 i][64 o] = dx[32 i][64 e] @ Wdec[o][h*64+e]^T
  f32x16 Co0, Co1;
#pragma unroll
  for (int r = 0; r < 16; ++r) { Co0[r] = 0.f; Co1[r] = 0.f; }
#pragma unroll
  for (int ks = 0; ks < 4; ++ks) {
    f16x8 aD = *(f16x8*)&dxw[m31 * AST + ks * 16 + hf * 8];  // wave-local read-after-write
    f16x8 w0 = *(const f16x8*)&Wdf[(size_t)m31 * 256 + h * 64 + ks * 16 + hf * 8];
    f16x8 w1 = *(const f16x8*)&Wdf[(size_t)(32 + m31) * 256 + h * 64 + ks * 16 + hf * 8];
    Co0 = __builtin_amdgcn_mfma_f32_32x32x16_f16(aD, w0, Co0, 0, 0, 0);
    Co1 = __builtin_amdgcn_mfma_f32_32x32x16_f16(aD, w1, Co1, 0, 0, 0);
  }

  // head-sum into LDS accumulator (4 head-waves)
#pragma unroll
  for (int r = 0; r < 16; ++r) {
    const int rr = (r & 3) + 8 * (r >> 2) + 4 * hf;
    atomicAdd(&outacc[rr * OST + m31], Co0[r]);
    atomicAdd(&outacc[rr * OST + 32 + m31], Co1[r]);
  }
  __syncthreads();

  // store: out[n, i0+row, :] = outacc[row] + bdec (block fully owns these 32 rows)
#pragma unroll
  for (int rep = 0; rep < 2; ++rep) {
    const int idx = rep * 256 + t;
    const int row = idx >> 4, c4 = (idx & 15) * 4;
    float4 v;
    v.x = outacc[row * OST + c4 + 0] + bdec[c4 + 0];
    v.y = outacc[row * OST + c4 + 1] + bdec[c4 + 1];
    v.z = outacc[row * OST + c4 + 2] + bdec[c4 + 2];
    v.w = outacc[row * OST + c4 + 3] + bdec[c4 + 3];
    *(float4*)&out[((size_t)n * MM + i0 + row) * DD + c4] = v;
  }
}

extern "C" void kernel_launch(void* const* d_in, const int* in_sizes, int n_in,
                              void* d_out, int out_size, void* d_ws, size_t ws_size,
                              hipStream_t stream) {
  const float* x    = (const float*)d_in[0];
  const float* Wk   = (const float*)d_in[2];
  const float* bk   = (const float*)d_in[3];
  const float* Wq   = (const float*)d_in[4];
  const float* bq   = (const float*)d_in[5];
  const float* Wv   = (const float*)d_in[6];
  const float* bv   = (const float*)d_in[7];
  const float* Wdec = (const float*)d_in[8];
  const float* bdec = (const float*)d_in[9];
  float* out = (float*)d_out;

  const size_t seg = (size_t)NB * HH * MM * DD;
  unsigned short* Kf  = (unsigned short*)d_ws;
  unsigned short* Qf  = Kf + seg;
  unsigned short* Vt  = Qf + seg;
  unsigned short* DXp = Vt + seg;  // unused (dec fused); kept for ws layout stability
  unsigned short* Wf  = DXp + seg;
  unsigned short* Wdf = Wf + 3 * 16384;

  prep_kernel<<<64, 256, 0, stream>>>(Wk, Wq, Wv, Wdec, Wf);
  proj_kernel<<<dim3(256, 12), 256, 0, stream>>>(x, Wf, bk, bq, bv, Kf, Qf, Vt);
  attn_kernel<<<dim3(32, 16), 256, 0, stream>>>(Kf, Qf, Vt, x, Wdf, bdec, out);
}

// Round 11
// 161.701 us; speedup vs baseline: 1.0031x; 1.0020x over previous
//
#include <hip/hip_runtime.h>
#include <hip/hip_bf16.h>

// Node_GAT N=16, M=1024, D=64, H=4.
// R15 = R14 + amdgpu_waves_per_eu(2,2) on attn_kernel — single change.
// Diagnosis: R13/R14 both compiled attn at VGPR=120 (just under 128 = the 4-waves/SIMD
// boundary). The compiler's occupancy heuristic targets 4 waves/EU when the epilogue
// is present, sinking the reg-dbuf prefetch loads to their uses (pipeline deleted,
// attn 58us, MfmaUtil 11). Grid is 512 blocks = 2 blocks/CU, so >2 waves/EU is
// unusable anyway: pin waves/EU to exactly 2 -> full 256-VGPR budget, loads stay live.
// Everything else byte-identical to R14 (dec fused, DX deleted, LDS-free j-loop,
// frag-major Q/V^T, reg double-buffer, XCD swizzle, K pre-scaled by log2e).

#define NB 16
#define MM 1024
#define DD 64
#define HH 4
#define NEG 0.2f
#define AST 72   // LDS row stride (shorts): 16B-aligned rows
#define OST 65   // out-accum LDS stride (floats)
#define LOG2E 1.44269504088896f

typedef __attribute__((ext_vector_type(8))) short bf16x8;
typedef __attribute__((ext_vector_type(8))) _Float16 f16x8;
typedef __attribute__((ext_vector_type(16))) float f32x16;
typedef __attribute__((ext_vector_type(4))) unsigned int uint4v;
typedef __attribute__((ext_vector_type(2))) unsigned int uint2v;

__device__ inline unsigned short f2bf(float f) {
  unsigned int u = __builtin_bit_cast(unsigned int, f);
  unsigned int r = (u + 0x7FFFu + ((u >> 16) & 1u)) >> 16;
  return (unsigned short)r;
}
__device__ inline unsigned short f2h(float f) {
  _Float16 h = (_Float16)f;
  return __builtin_bit_cast(unsigned short, h);
}
__device__ inline unsigned int pk_bf16(float lo, float hi) {
  unsigned int r;
  asm("v_cvt_pk_bf16_f32 %0, %1, %2" : "=v"(r) : "v"(lo), "v"(hi));
  return r;
}
// swap32(a,b): a' = {hf0: own.a, hf1: partner.b}; b' = {hf0: partner.a, hf1: own.b}
__device__ inline void swap32(unsigned int& a, unsigned int& b) {
  uint2v r = __builtin_amdgcn_permlane32_swap(a, b, false, false);
  a = r.x;
  b = r.y;
}

// ---------------- Kernel 0: weight prep -> f16 ----------------
__global__ __launch_bounds__(256) void prep_kernel(
    const float* __restrict__ Wk, const float* __restrict__ Wq,
    const float* __restrict__ Wv, const float* __restrict__ Wdec,
    unsigned short* __restrict__ Wf) {
  const int idx = (blockIdx.x * 256 + threadIdx.x) * 4;
  const int seg = idx >> 14, local = idx & 16383;
  const float* src = seg == 0 ? Wk : seg == 1 ? Wq : seg == 2 ? Wv : Wdec;
  float4 v = *(const float4*)&src[local];
  unsigned short p[4] = {f2h(v.x), f2h(v.y), f2h(v.z), f2h(v.w)};
  *(uint2*)&Wf[idx] = *(uint2*)p;
}

// ---------------- Kernel 1: projections, f16 32x32x16 MFMA ----------------
// grid (256, 12): 64 m-rows x combo(mat*4+h). K (scaled by log2e) -> linear f16;
// Q -> FRAG-MAJOR f16; V -> FRAG-MAJOR V^T bf16.
__global__ __launch_bounds__(256) void proj_kernel(
    const float* __restrict__ x, const unsigned short* __restrict__ Wf,
    const float* __restrict__ bk, const float* __restrict__ bq, const float* __restrict__ bv,
    unsigned short* __restrict__ Kf, unsigned short* __restrict__ Qf,
    unsigned short* __restrict__ Vtg) {
  __shared__ unsigned short xs[64 * AST];
  __shared__ unsigned short ob[64 * AST];
  const int t = threadIdx.x;
  const int r0 = blockIdx.x * 64;
  const int combo = blockIdx.y, mat = combo >> 2, h = combo & 3;
  const int n = r0 >> 10, ml = r0 & 1023;
  const float* bias = mat == 0 ? bk : (mat == 1 ? bq : bv);

#pragma unroll
  for (int rep = 0; rep < 2; ++rep) {
    int idx = rep * 256 + t, row = idx >> 3, c8 = (idx & 7) * 8;
    float4 a = *(const float4*)&x[(size_t)(r0 + row) * DD + c8];
    float4 b = *(const float4*)&x[(size_t)(r0 + row) * DD + c8 + 4];
    unsigned short p[8] = {f2h(a.x), f2h(a.y), f2h(a.z), f2h(a.w),
                           f2h(b.x), f2h(b.y), f2h(b.z), f2h(b.w)};
    *(uint4*)&xs[row * AST + c8] = *(uint4*)p;
  }
  __syncthreads();

  const int w = t >> 6, lane = t & 63, m31 = lane & 31, hf = lane >> 5;
  const int mi = w >> 1, ne = w & 1;
  const int ecol = h * 64 + ne * 32 + m31;
  const float bb = bias[ecol];

  f32x16 C;
#pragma unroll
  for (int r = 0; r < 16; ++r) C[r] = 0.f;
#pragma unroll
  for (int ks = 0; ks < 4; ++ks) {
    f16x8 xa = *(f16x8*)&xs[(mi * 32 + m31) * AST + ks * 16 + hf * 8];
    f16x8 wb = *(const f16x8*)&Wf[(size_t)mat * 16384 + (size_t)ecol * DD + ks * 16 + hf * 8];
    C = __builtin_amdgcn_mfma_f32_32x32x16_f16(xa, wb, C, 0, 0, 0);
  }

  if (mat < 2) {
    const float ksc = (mat == 0) ? LOG2E : 1.0f;  // fold exp's log2e into K
#pragma unroll
    for (int r = 0; r < 16; ++r) {
      int rr = (r & 3) + 8 * (r >> 2) + 4 * hf;
      ob[(mi * 32 + rr) * AST + ne * 32 + m31] = f2h((C[r] + bb) * ksc);
    }
  } else {
    // V transposed staging: ob[e][m_local], bf16
#pragma unroll
    for (int r = 0; r < 16; ++r) {
      int rr = (r & 3) + 8 * (r >> 2) + 4 * hf;
      ob[(ne * 32 + m31) * AST + mi * 32 + rr] = f2bf(C[r] + bb);
    }
  }
  __syncthreads();

  if (mat == 0) {
    // K: linear (n,h,m,e) — attn reads kfrag once per block
    const size_t obase = (((size_t)n * HH + h) * MM + ml) * DD;
#pragma unroll
    for (int rep = 0; rep < 2; ++rep) {
      int idx = rep * 256 + t, row = idx >> 3, c8 = (idx & 7) * 8;
      *(uint4*)&Kf[obase + (size_t)row * DD + c8] = *(uint4*)&ob[row * AST + c8];
    }
  } else if (mat == 1) {
    // Q frag-major: dst short-offset = base + ml*64 + idx*8, where
    // idx = jb32l*256 + ks*64 + hf2*32 + mr  <->  frag (jb32=ml/32+jb32l, ks, hf2, mr)
    const size_t obase = (((size_t)n * HH + h) * MM + ml) * DD;
#pragma unroll
    for (int rep = 0; rep < 2; ++rep) {
      int idx = rep * 256 + t;
      int jb32l = idx >> 8, ks = (idx >> 6) & 3, hf2 = (idx >> 5) & 1, mr = idx & 31;
      *(uint4*)&Qf[obase + (size_t)idx * 8] =
          *(uint4*)&ob[(jb32l * 32 + mr) * AST + ks * 16 + hf2 * 8];
    }
  } else {
    // V^T frag-major: dst short-offset = baseT + (ml/64)*4096 + idx*8, where
    // idx = ks*128 + eh*64 + hf2*32 + mr  <->  frag (jt=ml/64, ks, eh, hf2, mr)
    const size_t obaseT = (((size_t)n * HH + h) * DD) * MM + (size_t)(ml >> 6) * 4096;
#pragma unroll
    for (int rep = 0; rep < 2; ++rep) {
      int idx = rep * 256 + t;
      int ks = idx >> 7, eh = (idx >> 6) & 1, hf2 = (idx >> 5) & 1, mr = idx & 31;
      *(uint4*)&Vtg[obaseT + (size_t)idx * 8] =
          *(uint4*)&ob[(eh * 32 + mr) * AST + ks * 16 + hf2 * 8];
    }
  }
}

// ---------------- Kernel 2: fused attention + decoder ----------------
// grid (32 iblk, 16 n), 256 thr = 4 waves; wave w = head h. Block owns 32 i-rows.
// j-loop per wave (identical to R12): 16 coalesced frag loads, reg double-buffer one
// tile ahead, S^T mfma(Q,K) + in-reg softmax + PV. Zero LDS / zero barriers in loop.
// Epilogue: dx -> wave-local LDS transpose -> dec MFMA (head slice of Wdec) ->
// ds_add_f32 head-sum -> barrier -> +bdec, coalesced fp32 out store.

#define LOADF(qa0_, qa1_, bv0_, bv1_, jtn)                         \
  do {                                                             \
    const unsigned short* Qj_ = Qp + (size_t)(jtn) * 4096;         \
    const unsigned short* Vj_ = Vp + (size_t)(jtn) * 4096;         \
    _Pragma("unroll") for (int ks = 0; ks < 4; ++ks) {             \
      qa0_[ks] = *(const f16x8*)&Qj_[ks * 512 + loff];             \
      qa1_[ks] = *(const f16x8*)&Qj_[2048 + ks * 512 + loff];      \
      bv0_[ks] = *(const bf16x8*)&Vj_[ks * 1024 + loff];           \
      bv1_[ks] = *(const bf16x8*)&Vj_[ks * 1024 + 512 + loff];     \
    }                                                              \
  } while (0)

#define SOFTPACK(C_, dst0_, dst1_)                                             \
  do {                                                                         \
    _Pragma("unroll") for (int r = 0; r < 16; ++r) {                           \
      float s = C_[r];                                                         \
      s = fmaxf(s, NEG * s);                                                   \
      s = __builtin_amdgcn_exp2f(s);                                           \
      lac += s;                                                                \
      C_[r] = s;                                                               \
    }                                                                          \
    {                                                                          \
      unsigned int p01 = pk_bf16(C_[0], C_[1]), p23 = pk_bf16(C_[2], C_[3]);   \
      unsigned int p45 = pk_bf16(C_[4], C_[5]), p67 = pk_bf16(C_[6], C_[7]);   \
      swap32(p01, p45);                                                        \
      swap32(p23, p67);                                                        \
      uint4v wlo = {p01, p23, p45, p67};                                       \
      dst0_ = __builtin_bit_cast(bf16x8, wlo);                                 \
      unsigned int p89 = pk_bf16(C_[8], C_[9]), pAB = pk_bf16(C_[10], C_[11]); \
      unsigned int pCD = pk_bf16(C_[12], C_[13]), pEF = pk_bf16(C_[14], C_[15]); \
      swap32(p89, pCD);                                                        \
      swap32(pAB, pEF);                                                        \
      uint4v whi = {p89, pAB, pCD, pEF};                                       \
      dst1_ = __builtin_bit_cast(bf16x8, whi);                                 \
    }                                                                          \
  } while (0)

#define COMPUTE(qa0_, qa1_, bv0_, bv1_)                                         \
  do {                                                                          \
    bf16x8 pa[4];                                                               \
    f32x16 C;                                                                   \
    _Pragma("unroll") for (int r = 0; r < 16; ++r) C[r] = 0.f;                  \
    _Pragma("unroll") for (int ks = 0; ks < 4; ++ks)                            \
        C = __builtin_amdgcn_mfma_f32_32x32x16_f16(qa0_[ks], kfrag[ks], C, 0, 0, 0); \
    SOFTPACK(C, pa[0], pa[1]);                                                  \
    _Pragma("unroll") for (int r = 0; r < 16; ++r) C[r] = 0.f;                  \
    _Pragma("unroll") for (int ks = 0; ks < 4; ++ks)                            \
        C = __builtin_amdgcn_mfma_f32_32x32x16_f16(qa1_[ks], kfrag[ks], C, 0, 0, 0); \
    SOFTPACK(C, pa[2], pa[3]);                                                  \
    _Pragma("unroll") for (int ks = 0; ks < 4; ++ks) {                          \
      agg0 = __builtin_amdgcn_mfma_f32_32x32x16_bf16(pa[ks], bv0_[ks], agg0, 0, 0, 0); \
      agg1 = __builtin_amdgcn_mfma_f32_32x32x16_bf16(pa[ks], bv1_[ks], agg1, 0, 0, 0); \
    }                                                                           \
  } while (0)

__global__ __launch_bounds__(256)
__attribute__((amdgpu_waves_per_eu(2, 2)))  // pin: stop occupancy-targeting load-sink
void attn_kernel(
    const unsigned short* __restrict__ Kf, const unsigned short* __restrict__ Qf,
    const unsigned short* __restrict__ Vtg, const float* __restrict__ x,
    const unsigned short* __restrict__ Wdf, const float* __restrict__ bdec,
    float* __restrict__ out) {
  __shared__ __align__(16) unsigned short dxs[4 * 32 * AST];  // per-wave dx transpose
  __shared__ float outacc[32 * OST];                          // head-sum accumulator

  const int t = threadIdx.x;
  const int w = t >> 6, lane = t & 63;   // w = head
  const int m31 = lane & 31, hf = lane >> 5;
  const int h = w;

  // XCD-bijective swizzle: each XCD owns 2 whole n's (all 32 iblocks each).
  const int slot = blockIdx.x + 32 * (int)blockIdx.y;  // 0..511
  const int val = (slot & 7) * 64 + (slot >> 3);
  const int n = val >> 5, ib = val & 31;
  const int i0 = ib * 32;

  // zero the out accumulator before epilogue use
  for (int idx = t; idx < 32 * OST; idx += 256) outacc[idx] = 0.f;

  const size_t base = (((size_t)n * HH + h) * MM) * DD;
  const size_t baseT = (((size_t)n * HH + h) * DD) * MM;
  const unsigned short* Qp = Qf + base;
  const unsigned short* Vp = Vtg + baseT;

  // K fragments: B-operand cols i = i0 + m31 (log2e pre-folded in proj)
  f16x8 kfrag[4];
#pragma unroll
  for (int ks = 0; ks < 4; ++ks)
    kfrag[ks] = *(const f16x8*)&Kf[base + (size_t)(i0 + m31) * DD + ks * 16 + hf * 8];

  f32x16 agg0, agg1;
#pragma unroll
  for (int r = 0; r < 16; ++r) { agg0[r] = 0.f; agg1[r] = 0.f; }
  float lac = 0.f;

  const int loff = hf * 256 + m31 * 8;  // lane term, shared by all frag loads

  // named double-buffer sets (all indices literal — rule #20)
  f16x8 Aq0[4], Aq1[4], Bq0[4], Bq1[4];
  bf16x8 Av0[4], Av1[4], Bv0[4], Bv1[4];

  LOADF(Aq0, Aq1, Av0, Av1, 0);
  for (int g = 0; g < 8; ++g) {
    LOADF(Bq0, Bq1, Bv0, Bv1, 2 * g + 1);             // prefetch odd tile
    COMPUTE(Aq0, Aq1, Av0, Av1);                      // compute even tile
    if (g < 7) LOADF(Aq0, Aq1, Av0, Av1, 2 * g + 2);  // prefetch next even tile
    COMPUTE(Bq0, Bq1, Bv0, Bv1);                      // compute odd tile
  }

  // denom: lsum(lane) = l[row m31] (both halves); broadcast to row rr via shfl.
  const float lsum = lac + __shfl_xor(lac, 32);

  // dx = leaky(agg/l) - x -> f16 into this wave's transpose region (lane=e -> lane=i)
  unsigned short* dxw = dxs + w * (32 * AST);
#pragma unroll
  for (int r = 0; r < 16; ++r) {
    const int rr = (r & 3) + 8 * (r >> 2) + 4 * hf;
    const float rl = 1.0f / __shfl(lsum, rr);
    const size_t xrow = ((size_t)n * MM + i0 + rr) * DD;
    float v0 = agg0[r] * rl;
    v0 = fmaxf(v0, NEG * v0);
    v0 -= x[xrow + m31];
    dxw[rr * AST + m31] = f2h(v0);
    float v1 = agg1[r] * rl;
    v1 = fmaxf(v1, NEG * v1);
    v1 -= x[xrow + 32 + m31];
    dxw[rr * AST + 32 + m31] = f2h(v1);
  }

  // dec partial: out_part[32 i][64 o] = dx[32 i][64 e] @ Wdec[o][h*64+e]^T
  f32x16 Co0, Co1;
#pragma unroll
  for (int r = 0; r < 16; ++r) { Co0[r] = 0.f; Co1[r] = 0.f; }
#pragma unroll
  for (int ks = 0; ks < 4; ++ks) {
    f16x8 aD = *(f16x8*)&dxw[m31 * AST + ks * 16 + hf * 8];  // wave-local read-after-write
    f16x8 w0 = *(const f16x8*)&Wdf[(size_t)m31 * 256 + h * 64 + ks * 16 + hf * 8];
    f16x8 w1 = *(const f16x8*)&Wdf[(size_t)(32 + m31) * 256 + h * 64 + ks * 16 + hf * 8];
    Co0 = __builtin_amdgcn_mfma_f32_32x32x16_f16(aD, w0, Co0, 0, 0, 0);
    Co1 = __builtin_amdgcn_mfma_f32_32x32x16_f16(aD, w1, Co1, 0, 0, 0);
  }

  // head-sum into LDS accumulator (4 head-waves)
#pragma unroll
  for (int r = 0; r < 16; ++r) {
    const int rr = (r & 3) + 8 * (r >> 2) + 4 * hf;
    atomicAdd(&outacc[rr * OST + m31], Co0[r]);
    atomicAdd(&outacc[rr * OST + 32 + m31], Co1[r]);
  }
  __syncthreads();

  // store: out[n, i0+row, :] = outacc[row] + bdec (block fully owns these 32 rows)
#pragma unroll
  for (int rep = 0; rep < 2; ++rep) {
    const int idx = rep * 256 + t;
    const int row = idx >> 4, c4 = (idx & 15) * 4;
    float4 v;
    v.x = outacc[row * OST + c4 + 0] + bdec[c4 + 0];
    v.y = outacc[row * OST + c4 + 1] + bdec[c4 + 1];
    v.z = outacc[row * OST + c4 + 2] + bdec[c4 + 2];
    v.w = outacc[row * OST + c4 + 3] + bdec[c4 + 3];
    *(float4*)&out[((size_t)n * MM + i0 + row) * DD + c4] = v;
  }
}

extern "C" void kernel_launch(void* const* d_in, const int* in_sizes, int n_in,
                              void* d_out, int out_size, void* d_ws, size_t ws_size,
                              hipStream_t stream) {
  const float* x    = (const float*)d_in[0];
  const float* Wk   = (const float*)d_in[2];
  const float* bk   = (const float*)d_in[3];
  const float* Wq   = (const float*)d_in[4];
  const float* bq   = (const float*)d_in[5];
  const float* Wv   = (const float*)d_in[6];
  const float* bv   = (const float*)d_in[7];
  const float* Wdec = (const float*)d_in[8];
  const float* bdec = (const float*)d_in[9];
  float* out = (float*)d_out;

  const size_t seg = (size_t)NB * HH * MM * DD;
  unsigned short* Kf  = (unsigned short*)d_ws;
  unsigned short* Qf  = Kf + seg;
  unsigned short* Vt  = Qf + seg;
  unsigned short* DXp = Vt + seg;  // unused (dec fused); kept for ws layout stability
  unsigned short* Wf  = DXp + seg;
  unsigned short* Wdf = Wf + 3 * 16384;

  prep_kernel<<<64, 256, 0, stream>>>(Wk, Wq, Wv, Wdec, Wf);
  proj_kernel<<<dim3(256, 12), 256, 0, stream>>>(x, Wf, bk, bq, bv, Kf, Qf, Vt);
  attn_kernel<<<dim3(32, 16), 256, 0, stream>>>(Kf, Qf, Vt, x, Wdf, bdec, out);
}

// Round 12
// 156.126 us; speedup vs baseline: 1.0389x; 1.0357x over previous
//
#include <hip/hip_runtime.h>
#include <hip/hip_bf16.h>

// Node_GAT N=16, M=1024, D=64, H=4.
// R16 = revert to R10 (best-known, 149.5us: LDS-staged deferred-PV attn + separate dec)
// + delete prep_kernel: proj and dec convert weight fragments f32->f16 ON THE FLY in
// registers (32 v_cvt per lane, hidden under MFMA; W is L2-resident 0.8MB). Removes one
// dispatch + one launch gap + the Wf write/readback. Numerics identical (same f2h point
// arithmetic, different location). Fusion branch (R13-R15) abandoned per pre-commit:
// compiler sinks the reg-dbuf prefetch loads whenever the dec epilogue is present
// (VGPR pinned ~120-124 across 3 structural variants).

#define NB 16
#define MM 1024
#define DD 64
#define HH 4
#define NEG 0.2f
#define AST 72   // LDS row stride (shorts): 16B-aligned rows
#define SLOT (64 * AST)
#define DST 264  // dec LDS stride (256-wide rows)
#define LOG2E 1.44269504088896f

typedef __attribute__((ext_vector_type(8))) short bf16x8;
typedef __attribute__((ext_vector_type(8))) _Float16 f16x8;
typedef __attribute__((ext_vector_type(16))) float f32x16;
typedef __attribute__((ext_vector_type(4))) unsigned int uint4v;
typedef __attribute__((ext_vector_type(2))) unsigned int uint2v;

__device__ inline unsigned short f2bf(float f) {
  unsigned int u = __builtin_bit_cast(unsigned int, f);
  unsigned int r = (u + 0x7FFFu + ((u >> 16) & 1u)) >> 16;
  return (unsigned short)r;
}
__device__ inline unsigned short f2h(float f) {
  _Float16 h = (_Float16)f;
  return __builtin_bit_cast(unsigned short, h);
}
__device__ inline unsigned int pk_bf16(float lo, float hi) {
  unsigned int r;
  asm("v_cvt_pk_bf16_f32 %0, %1, %2" : "=v"(r) : "v"(lo), "v"(hi));
  return r;
}
// swap32(a,b): a' = {hf0: own.a, hf1: partner.b}; b' = {hf0: partner.a, hf1: own.b}
__device__ inline void swap32(unsigned int& a, unsigned int& b) {
  uint2v r = __builtin_amdgcn_permlane32_swap(a, b, false, false);
  a = r.x;
  b = r.y;
}
// load 8 consecutive f32 and convert to f16x8 (on-the-fly weight conversion)
__device__ inline f16x8 ldcvt_f16x8(const float* p) {
  float4 a = *(const float4*)p;
  float4 b = *(const float4*)(p + 4);
  f16x8 r;
  r[0] = (_Float16)a.x; r[1] = (_Float16)a.y; r[2] = (_Float16)a.z; r[3] = (_Float16)a.w;
  r[4] = (_Float16)b.x; r[5] = (_Float16)b.y; r[6] = (_Float16)b.z; r[7] = (_Float16)b.w;
  return r;
}

// ---------------- Kernel 1: projections, f16 32x32x16 MFMA ----------------
// grid (256, 12): 64 m-rows x combo(mat*4+h). K (scaled by log2e), Q -> f16 (n,h,m,e);
// V -> bf16 Vt (n,h,e,m). Weights converted f32->f16 in registers at load.
__global__ __launch_bounds__(256) void proj_kernel(
    const float* __restrict__ x,
    const float* __restrict__ Wk, const float* __restrict__ Wq, const float* __restrict__ Wv,
    const float* __restrict__ bk, const float* __restrict__ bq, const float* __restrict__ bv,
    unsigned short* __restrict__ Kf, unsigned short* __restrict__ Qf,
    unsigned short* __restrict__ Vtg) {
  __shared__ unsigned short xs[64 * AST];
  __shared__ unsigned short ob[64 * AST];
  const int t = threadIdx.x;
  const int r0 = blockIdx.x * 64;
  const int combo = blockIdx.y, mat = combo >> 2, h = combo & 3;
  const int n = r0 >> 10, ml = r0 & 1023;
  const float* bias = mat == 0 ? bk : (mat == 1 ? bq : bv);
  const float* Wsrc = mat == 0 ? Wk : (mat == 1 ? Wq : Wv);

#pragma unroll
  for (int rep = 0; rep < 2; ++rep) {
    int idx = rep * 256 + t, row = idx >> 3, c8 = (idx & 7) * 8;
    float4 a = *(const float4*)&x[(size_t)(r0 + row) * DD + c8];
    float4 b = *(const float4*)&x[(size_t)(r0 + row) * DD + c8 + 4];
    unsigned short p[8] = {f2h(a.x), f2h(a.y), f2h(a.z), f2h(a.w),
                           f2h(b.x), f2h(b.y), f2h(b.z), f2h(b.w)};
    *(uint4*)&xs[row * AST + c8] = *(uint4*)p;
  }
  __syncthreads();

  const int w = t >> 6, lane = t & 63, m31 = lane & 31, hf = lane >> 5;
  const int mi = w >> 1, ne = w & 1;
  const int ecol = h * 64 + ne * 32 + m31;
  const float bb = bias[ecol];

  f32x16 C;
#pragma unroll
  for (int r = 0; r < 16; ++r) C[r] = 0.f;
#pragma unroll
  for (int ks = 0; ks < 4; ++ks) {
    f16x8 xa = *(f16x8*)&xs[(mi * 32 + m31) * AST + ks * 16 + hf * 8];
    f16x8 wb = ldcvt_f16x8(&Wsrc[(size_t)ecol * DD + ks * 16 + hf * 8]);
    C = __builtin_amdgcn_mfma_f32_32x32x16_f16(xa, wb, C, 0, 0, 0);
  }

  if (mat < 2) {
    const float ksc = (mat == 0) ? LOG2E : 1.0f;  // fold exp's log2e into K
#pragma unroll
    for (int r = 0; r < 16; ++r) {
      int rr = (r & 3) + 8 * (r >> 2) + 4 * hf;
      ob[(mi * 32 + rr) * AST + ne * 32 + m31] = f2h((C[r] + bb) * ksc);
    }
  } else {
    // V transposed staging: ob[e][m_local], bf16
#pragma unroll
    for (int r = 0; r < 16; ++r) {
      int rr = (r & 3) + 8 * (r >> 2) + 4 * hf;
      ob[(ne * 32 + m31) * AST + mi * 32 + rr] = f2bf(C[r] + bb);
    }
  }
  __syncthreads();

  if (mat < 2) {
    unsigned short* dst = mat == 0 ? Kf : Qf;
    const size_t obase = (((size_t)n * HH + h) * MM + ml) * DD;
#pragma unroll
    for (int rep = 0; rep < 2; ++rep) {
      int idx = rep * 256 + t, row = idx >> 3, c8 = (idx & 7) * 8;
      *(uint4*)&dst[obase + (size_t)row * DD + c8] = *(uint4*)&ob[row * AST + c8];
    }
  } else {
    const size_t obase = (((size_t)n * HH + h) * DD) * MM + ml;
#pragma unroll
    for (int rep = 0; rep < 2; ++rep) {
      int idx = rep * 256 + t, row = idx >> 3, c8 = (idx & 7) * 8;
      *(uint4*)&Vtg[obase + (size_t)row * MM + c8] = *(uint4*)&ob[row * AST + c8];
    }
  }
}

// ---------------- Kernel 2: flash attention, wave-local P + deferred PV ----------------
// grid (8, H, N), 256 thr = 4 waves. Block: 128 i x 1024 j; wave w owns i-strip w*32..+32.
// Iter jt: S^T(jt) tile0 -> softmax(t0) -> PV(jt-1) [independent: overlaps softmax] ->
// S^T(jt) tile1 -> softmax(t1) -> stage jt+1 -> barrier. Final PV after loop.
// Q: 2 LDS slots; V: 4 LDS slots (PV reads slot jt-1 while slot jt+1 is written).
__global__ __launch_bounds__(256, 2) void attn_kernel(
    const unsigned short* __restrict__ Kf, const unsigned short* __restrict__ Qf,
    const unsigned short* __restrict__ Vtg, const float* __restrict__ x,
    unsigned short* __restrict__ DX) {
  __shared__ __align__(16) unsigned short sm[6 * SLOT];  // q[2] | v[4]; epilogue reuses
  __shared__ float ls[128];                              // per-row softmax denom

  const int t = threadIdx.x;
  const int w = t >> 6, lane = t & 63;
  const int m31 = lane & 31, hf = lane >> 5;

  // XCD-bijective swizzle: xcd = slot&7 gets 8 whole (n,h) groups.
  const int slot = blockIdx.x + 8 * (blockIdx.y + HH * (int)blockIdx.z);  // 0..511
  const int xcd = slot & 7, within = slot >> 3;
  const int grp = xcd * 8 + (within >> 3);  // 0..63 = n*4+h
  const int ib = within & 7;
  const int n = grp >> 2, h = grp & 3;
  const int i0 = ib * 128;

  const size_t base = (((size_t)n * HH + h) * MM) * DD;
  const size_t baseT = (((size_t)n * HH + h) * DD) * MM;
  const unsigned short* Qp = Qf + base;
  const unsigned short* Vp = Vtg + baseT;

  unsigned short* qs = sm;             // 2 slots
  unsigned short* vs = sm + 2 * SLOT;  // 4 slots

  // K fragments: B-operand cols i = i0 + w*32 + m31 (log2e pre-folded in proj)
  f16x8 kfrag[4];
#pragma unroll
  for (int ks = 0; ks < 4; ++ks)
    kfrag[ks] = *(const f16x8*)&Kf[base + (size_t)(i0 + w * 32 + m31) * DD + ks * 16 + hf * 8];

  const int r0 = t >> 3, c8 = (t & 7) * 8;

  // prologue: stage tile 0 into q slot 0 / v slot 0
  {
    uint4 qa = *(const uint4*)&Qp[(size_t)r0 * DD + c8];
    uint4 qb2 = *(const uint4*)&Qp[(size_t)(r0 + 32) * DD + c8];
    uint4 va = *(const uint4*)&Vp[(size_t)r0 * MM + c8];
    uint4 vb2 = *(const uint4*)&Vp[(size_t)(r0 + 32) * MM + c8];
    *(uint4*)&qs[r0 * AST + c8] = qa;
    *(uint4*)&qs[(r0 + 32) * AST + c8] = qb2;
    *(uint4*)&vs[r0 * AST + c8] = va;
    *(uint4*)&vs[(r0 + 32) * AST + c8] = vb2;
  }
  __syncthreads();

  f32x16 agg0, agg1;
#pragma unroll
  for (int r = 0; r < 16; ++r) { agg0[r] = 0.f; agg1[r] = 0.f; }
  float lac = 0.f;

  uint4 qrA, qrB, vrA, vrB;
  bf16x8 pa[2][4];  // [jt&1][ks] — all indices compile-time via g*4+k nest

  for (int g = 0; g < 4; ++g) {
#pragma unroll
    for (int k = 0; k < 4; ++k) {
      const int jt = g * 4 + k;
      unsigned short* qb = qs + (k & 1) * SLOT;
      const bool haveNext = (k < 3) || (g < 3);

      // issue global prefetch for tile jt+1 (lands during compute; written at tail)
      if (haveNext) {
        const int j0n = (jt + 1) * 64;
        qrA = *(const uint4*)&Qp[(size_t)(j0n + r0) * DD + c8];
        qrB = *(const uint4*)&Qp[(size_t)(j0n + r0 + 32) * DD + c8];
        vrA = *(const uint4*)&Vp[(size_t)r0 * MM + j0n + c8];
        vrB = *(const uint4*)&Vp[(size_t)(r0 + 32) * MM + j0n + c8];
      }

      // ---- S tile0: D[j][i] = mfma(Q rows j, K cols i) ----
      f32x16 C;
#pragma unroll
      for (int r = 0; r < 16; ++r) C[r] = 0.f;
#pragma unroll
      for (int ks = 0; ks < 4; ++ks) {
        f16x8 qa = *(f16x8*)&qb[m31 * AST + ks * 16 + hf * 8];
        C = __builtin_amdgcn_mfma_f32_32x32x16_f16(qa, kfrag[ks], C, 0, 0, 0);
      }
      // softmax t0 -> pa[k&1][0..1]
#pragma unroll
      for (int r = 0; r < 16; ++r) {
        float s = C[r];
        s = fmaxf(s, NEG * s);
        s = __builtin_amdgcn_exp2f(s);
        lac += s;
        C[r] = s;
      }
      {
        unsigned int p01 = pk_bf16(C[0], C[1]), p23 = pk_bf16(C[2], C[3]);
        unsigned int p45 = pk_bf16(C[4], C[5]), p67 = pk_bf16(C[6], C[7]);
        swap32(p01, p45);
        swap32(p23, p67);
        uint4v wlo = {p01, p23, p45, p67};
        pa[k & 1][0] = __builtin_bit_cast(bf16x8, wlo);
        unsigned int p89 = pk_bf16(C[8], C[9]), pAB = pk_bf16(C[10], C[11]);
        unsigned int pCD = pk_bf16(C[12], C[13]), pEF = pk_bf16(C[14], C[15]);
        swap32(p89, pCD);
        swap32(pAB, pEF);
        uint4v whi = {p89, pAB, pCD, pEF};
        pa[k & 1][1] = __builtin_bit_cast(bf16x8, whi);
      }

      // ---- deferred PV(jt-1): independent of this iter's S/softmax ----
      if ((k > 0) || (g > 0)) {
        unsigned short* vbp = vs + ((k + 3) & 3) * SLOT;  // slot (jt-1)&3
#pragma unroll
        for (int ks = 0; ks < 4; ++ks) {
          bf16x8 bv0 = *(bf16x8*)&vbp[m31 * AST + ks * 16 + hf * 8];
          bf16x8 bv1 = *(bf16x8*)&vbp[(32 + m31) * AST + ks * 16 + hf * 8];
          agg0 = __builtin_amdgcn_mfma_f32_32x32x16_bf16(pa[(k + 1) & 1][ks], bv0, agg0, 0, 0, 0);
          agg1 = __builtin_amdgcn_mfma_f32_32x32x16_bf16(pa[(k + 1) & 1][ks], bv1, agg1, 0, 0, 0);
        }
      }

      // ---- S tile1 + softmax -> pa[k&1][2..3] ----
#pragma unroll
      for (int r = 0; r < 16; ++r) C[r] = 0.f;
#pragma unroll
      for (int ks = 0; ks < 4; ++ks) {
        f16x8 qa = *(f16x8*)&qb[(32 + m31) * AST + ks * 16 + hf * 8];
        C = __builtin_amdgcn_mfma_f32_32x32x16_f16(qa, kfrag[ks], C, 0, 0, 0);
      }
#pragma unroll
      for (int r = 0; r < 16; ++r) {
        float s = C[r];
        s = fmaxf(s, NEG * s);
        s = __builtin_amdgcn_exp2f(s);
        lac += s;
        C[r] = s;
      }
      {
        unsigned int p01 = pk_bf16(C[0], C[1]), p23 = pk_bf16(C[2], C[3]);
        unsigned int p45 = pk_bf16(C[4], C[5]), p67 = pk_bf16(C[6], C[7]);
        swap32(p01, p45);
        swap32(p23, p67);
        uint4v wlo = {p01, p23, p45, p67};
        pa[k & 1][2] = __builtin_bit_cast(bf16x8, wlo);
        unsigned int p89 = pk_bf16(C[8], C[9]), pAB = pk_bf16(C[10], C[11]);
        unsigned int pCD = pk_bf16(C[12], C[13]), pEF = pk_bf16(C[14], C[15]);
        swap32(p89, pCD);
        swap32(pAB, pEF);
        uint4v whi = {p89, pAB, pCD, pEF};
        pa[k & 1][3] = __builtin_bit_cast(bf16x8, whi);
      }

      // stage tile jt+1: q slot (jt+1)&1, v slot (jt+1)&3
      if (haveNext) {
        unsigned short* qn = qs + ((k + 1) & 1) * SLOT;
        unsigned short* vn = vs + ((k + 1) & 3) * SLOT;
        *(uint4*)&qn[r0 * AST + c8] = qrA;
        *(uint4*)&qn[(r0 + 32) * AST + c8] = qrB;
        *(uint4*)&vn[r0 * AST + c8] = vrA;
        *(uint4*)&vn[(r0 + 32) * AST + c8] = vrB;
      }
      __syncthreads();
    }
  }

  // final PV for jt=15: pa[1], v slot 3
  {
    unsigned short* vbp = vs + 3 * SLOT;
#pragma unroll
    for (int ks = 0; ks < 4; ++ks) {
      bf16x8 bv0 = *(bf16x8*)&vbp[m31 * AST + ks * 16 + hf * 8];
      bf16x8 bv1 = *(bf16x8*)&vbp[(32 + m31) * AST + ks * 16 + hf * 8];
      agg0 = __builtin_amdgcn_mfma_f32_32x32x16_bf16(pa[1][ks], bv0, agg0, 0, 0, 0);
      agg1 = __builtin_amdgcn_mfma_f32_32x32x16_bf16(pa[1][ks], bv1, agg1, 0, 0, 0);
    }
  }

  // denom: lane's lac covers its crow-set for column i=m31; pair-sum gives full l[i=m31].
  const float lsum = lac + __shfl_xor(lac, 32);
  if (hf == 0) ls[w * 32 + m31] = lsum;
  __syncthreads();

  // epilogue: dx = leaky(agg/l) - x -> f16 stage in sm -> coalesced store (concat layout)
#pragma unroll
  for (int r = 0; r < 16; ++r) {
    const int rr = (r & 3) + 8 * (r >> 2) + 4 * hf;
    const float rl = 1.0f / ls[w * 32 + rr];
    const size_t xrow = ((size_t)n * MM + i0 + w * 32 + rr) * DD;
    float v0 = agg0[r] * rl;
    v0 = fmaxf(v0, NEG * v0);
    v0 -= x[xrow + m31];
    sm[(w * 32 + rr) * AST + m31] = f2h(v0);
    float v1 = agg1[r] * rl;
    v1 = fmaxf(v1, NEG * v1);
    v1 -= x[xrow + 32 + m31];
    sm[(w * 32 + rr) * AST + 32 + m31] = f2h(v1);
  }
  __syncthreads();
#pragma unroll
  for (int rep = 0; rep < 4; ++rep) {
    const int idx = rep * 256 + t, row = idx >> 3, cc = (idx & 7) * 8;
    *(uint4*)&DX[((size_t)n * MM + i0 + row) * (HH * DD) + h * DD + cc] =
        *(uint4*)&sm[row * AST + cc];
  }
}

// ---------------- Kernel 3: decoder, f16 32x32x16 MFMA ----------------
// Wdec converted f32->f16 in registers at load (row-major [o][256] matches Wdec layout).
__global__ __launch_bounds__(256) void dec_kernel(
    const unsigned short* __restrict__ DX, const float* __restrict__ Wdec,
    const float* __restrict__ bdec, float* __restrict__ out) {
  __shared__ unsigned short dxs[64 * DST];
  const int t = threadIdx.x;
  const int w = t >> 6, lane = t & 63, m31 = lane & 31, hf = lane >> 5;
  const int mi = w >> 1, nd = w & 1;
  const int r0 = blockIdx.x * 64;
#pragma unroll
  for (int rep = 0; rep < 8; ++rep) {
    int idx = rep * 256 + t, row = idx >> 5, c8 = (idx & 31) * 8;
    *(uint4*)&dxs[row * DST + c8] = *(const uint4*)&DX[(size_t)(r0 + row) * 256 + c8];
  }
  __syncthreads();
  const float bb = bdec[nd * 32 + m31];
  f32x16 C;
#pragma unroll
  for (int r = 0; r < 16; ++r) C[r] = 0.f;
#pragma unroll
  for (int ks = 0; ks < 16; ++ks) {
    f16x8 aD = *(f16x8*)&dxs[(mi * 32 + m31) * DST + ks * 16 + hf * 8];
    f16x8 bW = ldcvt_f16x8(&Wdec[(size_t)(nd * 32 + m31) * 256 + ks * 16 + hf * 8]);
    C = __builtin_amdgcn_mfma_f32_32x32x16_f16(aD, bW, C, 0, 0, 0);
  }
#pragma unroll
  for (int r = 0; r < 16; ++r) {
    int rr = (r & 3) + 8 * (r >> 2) + 4 * hf;
    out[(size_t)(r0 + mi * 32 + rr) * DD + nd * 32 + m31] = C[r] + bb;
  }
}

extern "C" void kernel_launch(void* const* d_in, const int* in_sizes, int n_in,
                              void* d_out, int out_size, void* d_ws, size_t ws_size,
                              hipStream_t stream) {
  const float* x    = (const float*)d_in[0];
  const float* Wk   = (const float*)d_in[2];
  const float* bk   = (const float*)d_in[3];
  const float* Wq   = (const float*)d_in[4];
  const float* bq   = (const float*)d_in[5];
  const float* Wv   = (const float*)d_in[6];
  const float* bv   = (const float*)d_in[7];
  const float* Wdec = (const float*)d_in[8];
  const float* bdec = (const float*)d_in[9];
  float* out = (float*)d_out;

  const size_t seg = (size_t)NB * HH * MM * DD;
  unsigned short* Kf  = (unsigned short*)d_ws;
  unsigned short* Qf  = Kf + seg;
  unsigned short* Vt  = Qf + seg;
  unsigned short* DXp = Vt + seg;

  proj_kernel<<<dim3(256, 12), 256, 0, stream>>>(x, Wk, Wq, Wv, bk, bq, bv, Kf, Qf, Vt);
  attn_kernel<<<dim3(8, HH, NB), 256, 0, stream>>>(Kf, Qf, Vt, x, DXp);
  dec_kernel<<<NB * MM / 64, 256, 0, stream>>>(DXp, Wdec, bdec, out);
}